// Round 1
// baseline (695.865 us; speedup 1.0000x reference)
//
#include <hip/hip_runtime.h>
#include <math.h>

#define DIM 512
#define NH  8
#define KQn 4
#define HQ  32      // NH*KQn
#define HD  64
#define BB  16
#define NN  8192
#define EPSLN 1e-6f

// workspace offsets (floats)
#define OFF_QKT    0                 // qkT[c][hq]  512*32
#define OFF_CB     16384             // [32]
#define OFF_L      16416             // [16][32]
#define OFF_POOLED 16928             // [16][32][512]
#define OFF_SCORES 279072            // [16][32][8192]

// ---------------- K1: precompute qk (scaled) and score bias c ----------------
__global__ __launch_bounds__(256) void pma_pre(
    const float* __restrict__ seed, const float* __restrict__ Wq, const float* __restrict__ bq,
    const float* __restrict__ Wk, const float* __restrict__ bk,
    float* __restrict__ qkT, float* __restrict__ cb)
{
    int hq = blockIdx.x; int h = hq >> 2; int j = hq & 3;
    int t = threadIdx.x;
    __shared__ float qpart[256];
    __shared__ float qloc[64];
    {
        int d = t >> 2, q4 = t & 3;
        const float* sr = seed + j*DIM + q4*128;
        const float* wr = Wq + (size_t)(h*HD + d)*DIM + q4*128;
        float acc = 0.f;
        for (int c = 0; c < 128; c += 4) {
            float4 s4 = *(const float4*)(sr + c);
            float4 w4 = *(const float4*)(wr + c);
            acc += s4.x*w4.x + s4.y*w4.y + s4.z*w4.z + s4.w*w4.w;
        }
        qpart[t] = acc;
    }
    __syncthreads();
    if (t < 64)
        qloc[t] = qpart[t*4] + qpart[t*4+1] + qpart[t*4+2] + qpart[t*4+3] + bq[h*HD + t];
    __syncthreads();
    for (int c = t; c < DIM; c += 256) {
        float acc = 0.f;
        #pragma unroll 8
        for (int d = 0; d < 64; ++d) acc += qloc[d] * Wk[(size_t)(h*HD + d)*DIM + c];
        qkT[c*HQ + hq] = acc * 0.125f;   // 1/sqrt(64)
    }
    if (t == 0) {
        float acc = 0.f;
        for (int d = 0; d < 64; ++d) acc += qloc[d] * bk[h*HD + d];
        cb[hq] = acc * 0.125f;
    }
}

// ---------------- K2: scores = X @ qkT + cb  (M=128 tile, K-tile 32) ----------------
__global__ __launch_bounds__(256) void pma_scores(
    const float* __restrict__ X, const float* __restrict__ qkT, const float* __restrict__ cb,
    float* __restrict__ scores)
{
    int mblk = blockIdx.x, b = blockIdx.y;
    int r0 = mblk * 128;
    int t = threadIdx.x;
    int rg = t & 31, hg = t >> 5;
    __shared__ float Xs[32][132];   // [kk][row], pad to 132
    __shared__ float qks[32][32];   // [kk][hq]
    float acc[4][4];
    #pragma unroll
    for (int i = 0; i < 4; ++i)
        #pragma unroll
        for (int j = 0; j < 4; ++j) acc[i][j] = 0.f;

    const float* Xb = X + ((size_t)b*NN + r0) * DIM;
    int srow = t >> 3;            // 0..31
    int koff = (t & 7) * 4;       // 0..28

    for (int kst = 0; kst < 16; ++kst) {
        int k0 = kst * 32;
        float4 xv[4];
        #pragma unroll
        for (int p = 0; p < 4; ++p)
            xv[p] = *(const float4*)(Xb + (size_t)(p*32 + srow)*DIM + k0 + koff);
        float qv[4];
        #pragma unroll
        for (int i = 0; i < 4; ++i) {
            int idx = i*256 + t;   // contiguous: (k0+kk)*32 + hq
            qv[i] = qkT[(size_t)k0*HQ + idx];
        }
        __syncthreads();          // previous stage's compute done
        #pragma unroll
        for (int p = 0; p < 4; ++p) {
            int r = p*32 + srow;
            Xs[koff+0][r] = xv[p].x;
            Xs[koff+1][r] = xv[p].y;
            Xs[koff+2][r] = xv[p].z;
            Xs[koff+3][r] = xv[p].w;
        }
        #pragma unroll
        for (int i = 0; i < 4; ++i) {
            int idx = i*256 + t;
            qks[idx >> 5][idx & 31] = qv[i];
        }
        __syncthreads();
        #pragma unroll
        for (int kk = 0; kk < 32; ++kk) {
            float4 x4 = *(const float4*)&Xs[kk][rg*4];
            float4 q4 = *(const float4*)&qks[kk][hg*4];
            acc[0][0] += x4.x*q4.x; acc[0][1] += x4.x*q4.y; acc[0][2] += x4.x*q4.z; acc[0][3] += x4.x*q4.w;
            acc[1][0] += x4.y*q4.x; acc[1][1] += x4.y*q4.y; acc[1][2] += x4.y*q4.z; acc[1][3] += x4.y*q4.w;
            acc[2][0] += x4.z*q4.x; acc[2][1] += x4.z*q4.y; acc[2][2] += x4.z*q4.z; acc[2][3] += x4.z*q4.w;
            acc[3][0] += x4.w*q4.x; acc[3][1] += x4.w*q4.y; acc[3][2] += x4.w*q4.z; acc[3][3] += x4.w*q4.w;
        }
    }
    #pragma unroll
    for (int j = 0; j < 4; ++j) {
        int hq = hg*4 + j;
        float cbv = cb[hq];
        float4 o;
        o.x = acc[0][j] + cbv; o.y = acc[1][j] + cbv;
        o.z = acc[2][j] + cbv; o.w = acc[3][j] + cbv;
        *(float4*)&scores[((size_t)b*HQ + hq)*NN + r0 + rg*4] = o;
    }
}

// ---------------- K3: softmax numerator per (b,hq) row; stores exp(s-m), l ----------------
__global__ __launch_bounds__(256) void pma_softmax(
    float* __restrict__ scores, float* __restrict__ lsum)
{
    int hq = blockIdx.x, b = blockIdx.y;
    int t = threadIdx.x;
    float* row = scores + ((size_t)b*HQ + hq)*NN;
    __shared__ float red[256];
    float4 v[8];
    float m = -1e30f;
    #pragma unroll
    for (int i = 0; i < 8; ++i) {
        v[i] = *(const float4*)(row + (size_t)(i*256 + t)*4);
        m = fmaxf(m, fmaxf(fmaxf(v[i].x, v[i].y), fmaxf(v[i].z, v[i].w)));
    }
    red[t] = m; __syncthreads();
    for (int s = 128; s > 0; s >>= 1) { if (t < s) red[t] = fmaxf(red[t], red[t+s]); __syncthreads(); }
    m = red[0];
    __syncthreads();
    float sum = 0.f;
    #pragma unroll
    for (int i = 0; i < 8; ++i) {
        float4 p;
        p.x = __expf(v[i].x - m); p.y = __expf(v[i].y - m);
        p.z = __expf(v[i].z - m); p.w = __expf(v[i].w - m);
        sum += p.x + p.y + p.z + p.w;
        *(float4*)(row + (size_t)(i*256 + t)*4) = p;
    }
    red[t] = sum; __syncthreads();
    for (int s = 128; s > 0; s >>= 1) { if (t < s) red[t] += red[t+s]; __syncthreads(); }
    if (t == 0) lsum[b*HQ + hq] = red[0];
}

// ---------------- K4: pooled[b][hq][c] += sum_n p[b][hq][n] * X[b][n][c] ----------------
#define ACC4(aj, pp, xx) { aj[0] += (pp)*(xx).x; aj[1] += (pp)*(xx).y; aj[2] += (pp)*(xx).z; aj[3] += (pp)*(xx).w; }

__global__ __launch_bounds__(256) void pma_pool(
    const float* __restrict__ X, const float* __restrict__ scores,
    float* __restrict__ pooled)
{
    int ks = blockIdx.x, b = blockIdx.y;
    int r0 = ks * 256;
    int t = threadIdx.x;
    int hg = t >> 5, cg = t & 31;
    __shared__ float p_s[32][256];   // [hq][n_local]
    __shared__ float Xs[8][516];     // [n_sub][c]
    float acc[4][4][4];              // [j(hq)][m(c-block)][cc]
    #pragma unroll
    for (int j = 0; j < 4; ++j)
        #pragma unroll
        for (int mm = 0; mm < 4; ++mm)
            #pragma unroll
            for (int cc = 0; cc < 4; ++cc) acc[j][mm][cc] = 0.f;

    #pragma unroll
    for (int i = 0; i < 32; ++i) {
        int idx = i*256 + t;         // hq = idx>>8, n = idx&255
        p_s[idx >> 8][idx & 255] = scores[((size_t)b*HQ + (idx >> 8))*NN + r0 + (idx & 255)];
    }
    const float* Xb = X + ((size_t)b*NN + r0) * DIM;

    for (int st = 0; st < 32; ++st) {
        float4 xv[4];
        #pragma unroll
        for (int i = 0; i < 4; ++i) {
            int slot = i*256 + t;    // 8 rows x 128 float4s
            int row = slot >> 7, c4 = (slot & 127) * 4;
            xv[i] = *(const float4*)(Xb + (size_t)(st*8 + row)*DIM + c4);
        }
        __syncthreads();             // prior compute done (also covers p_s on st==0)
        #pragma unroll
        for (int i = 0; i < 4; ++i) {
            int slot = i*256 + t;
            int row = slot >> 7, c4 = (slot & 127) * 4;
            *(float4*)&Xs[row][c4] = xv[i];
        }
        __syncthreads();
        #pragma unroll
        for (int k = 0; k < 8; ++k) {
            int kn = st*8 + k;
            float p0 = p_s[hg*4+0][kn];
            float p1 = p_s[hg*4+1][kn];
            float p2 = p_s[hg*4+2][kn];
            float p3 = p_s[hg*4+3][kn];
            float4 x0 = *(const float4*)&Xs[k][cg*4];
            float4 x1 = *(const float4*)&Xs[k][cg*4 + 128];
            float4 x2 = *(const float4*)&Xs[k][cg*4 + 256];
            float4 x3 = *(const float4*)&Xs[k][cg*4 + 384];
            ACC4(acc[0][0], p0, x0); ACC4(acc[0][1], p0, x1); ACC4(acc[0][2], p0, x2); ACC4(acc[0][3], p0, x3);
            ACC4(acc[1][0], p1, x0); ACC4(acc[1][1], p1, x1); ACC4(acc[1][2], p1, x2); ACC4(acc[1][3], p1, x3);
            ACC4(acc[2][0], p2, x0); ACC4(acc[2][1], p2, x1); ACC4(acc[2][2], p2, x2); ACC4(acc[2][3], p2, x3);
            ACC4(acc[3][0], p3, x0); ACC4(acc[3][1], p3, x1); ACC4(acc[3][2], p3, x2); ACC4(acc[3][3], p3, x3);
        }
    }
    #pragma unroll
    for (int j = 0; j < 4; ++j) {
        float* dst = pooled + ((size_t)b*HQ + hg*4 + j)*DIM + cg*4;
        #pragma unroll
        for (int mm = 0; mm < 4; ++mm) {
            atomicAdd(dst + mm*128 + 0, acc[j][mm][0]);
            atomicAdd(dst + mm*128 + 1, acc[j][mm][1]);
            atomicAdd(dst + mm*128 + 2, acc[j][mm][2]);
            atomicAdd(dst + mm*128 + 3, acc[j][mm][3]);
        }
    }
}

// ---------------- K5: Wv proj, Wo proj, residual + LayerNorm ----------------
__global__ __launch_bounds__(256) void pma_epilogue(
    const float* __restrict__ seed, const float* __restrict__ Wv, const float* __restrict__ bv,
    const float* __restrict__ Wo, const float* __restrict__ bo,
    const float* __restrict__ gamma, const float* __restrict__ beta,
    const float* __restrict__ pooled, const float* __restrict__ lsum,
    float* __restrict__ out)
{
    int j = blockIdx.x, b = blockIdx.y;
    int t = threadIdx.x;
    __shared__ float pooled_s[8][512];
    __shared__ float outv_s[512];
    __shared__ float h2_s[512];
    __shared__ float red[256];
    __shared__ float linv[8];
    if (t < 8) linv[t] = 1.f / lsum[b*HQ + t*4 + j];
    __syncthreads();
    #pragma unroll
    for (int i = 0; i < 16; ++i) {
        int idx = i*256 + t;        // 0..4095
        int h = idx >> 9, c = idx & 511;
        pooled_s[h][c] = pooled[((size_t)b*HQ + h*4 + j)*DIM + c] * linv[h];
    }
    __syncthreads();
    #pragma unroll
    for (int i = 0; i < 2; ++i) {
        int o = i*256 + t;
        int h = o >> 6;
        const float* wr = Wv + (size_t)o*DIM;
        float accv = bv[o];
        for (int c = 0; c < DIM; c += 4) {
            float4 pv = *(const float4*)&pooled_s[h][c];
            float4 wv = *(const float4*)(wr + c);
            accv += pv.x*wv.x + pv.y*wv.y + pv.z*wv.z + pv.w*wv.w;
        }
        outv_s[o] = accv;
    }
    __syncthreads();
    #pragma unroll
    for (int i = 0; i < 2; ++i) {
        int o = i*256 + t;
        const float* wr = Wo + (size_t)o*DIM;
        float acco = bo[o];
        for (int c = 0; c < DIM; c += 4) {
            float4 pv = *(const float4*)&outv_s[c];
            float4 wv = *(const float4*)(wr + c);
            acco += pv.x*wv.x + pv.y*wv.y + pv.z*wv.z + pv.w*wv.w;
        }
        h2_s[o] = acco + seed[j*DIM + o];
    }
    __syncthreads();
    float v0 = h2_s[t], v1 = h2_s[t + 256];
    red[t] = v0 + v1; __syncthreads();
    for (int s = 128; s > 0; s >>= 1) { if (t < s) red[t] += red[t+s]; __syncthreads(); }
    float mu = red[0] * (1.f/512.f);
    __syncthreads();
    red[t] = v0*v0 + v1*v1; __syncthreads();
    for (int s = 128; s > 0; s >>= 1) { if (t < s) red[t] += red[t+s]; __syncthreads(); }
    float var = red[0] * (1.f/512.f) - mu*mu;
    float rs = rsqrtf(var + EPSLN);
    float* orow = out + ((size_t)b*KQn + j)*DIM;
    orow[t]       = (v0 - mu)*rs*gamma[t]       + beta[t];
    orow[t + 256] = (v1 - mu)*rs*gamma[t + 256] + beta[t + 256];
}

extern "C" void kernel_launch(void* const* d_in, const int* in_sizes, int n_in,
                              void* d_out, int out_size, void* d_ws, size_t ws_size,
                              hipStream_t stream) {
    const float* X     = (const float*)d_in[0];
    const float* seed  = (const float*)d_in[1];
    const float* Wq    = (const float*)d_in[2];
    const float* bq    = (const float*)d_in[3];
    const float* Wk    = (const float*)d_in[4];
    const float* bk    = (const float*)d_in[5];
    const float* Wv    = (const float*)d_in[6];
    const float* bv    = (const float*)d_in[7];
    const float* Wo    = (const float*)d_in[8];
    const float* bo    = (const float*)d_in[9];
    const float* gamma = (const float*)d_in[10];
    const float* beta  = (const float*)d_in[11];
    float* ws     = (float*)d_ws;
    float* qkT    = ws + OFF_QKT;
    float* cb     = ws + OFF_CB;
    float* lsum   = ws + OFF_L;
    float* pooled = ws + OFF_POOLED;
    float* scores = ws + OFF_SCORES;
    float* out    = (float*)d_out;

    hipMemsetAsync(pooled, 0, (size_t)BB*HQ*DIM*sizeof(float), stream);
    pma_pre     <<<32,            256, 0, stream>>>(seed, Wq, bq, Wk, bk, qkT, cb);
    pma_scores  <<<dim3(64, 16),  256, 0, stream>>>(X, qkT, cb, scores);
    pma_softmax <<<dim3(32, 16),  256, 0, stream>>>(scores, lsum);
    pma_pool    <<<dim3(32, 16),  256, 0, stream>>>(X, scores, pooled);
    pma_epilogue<<<dim3(4, 16),   256, 0, stream>>>(seed, Wv, bv, Wo, bo, gamma, beta, pooled, lsum, out);
}

// Round 3
// 666.477 us; speedup vs baseline: 1.0441x; 1.0441x over previous
//
#include <hip/hip_runtime.h>
#include <math.h>

#define DIM 512
#define KQn 4
#define HQ  32
#define BB  16
#define NN  8192
#define EPSLN 1e-6f
#define NCHUNK 32
#define CROWS  256
#define TROWS  32
#define NTILE  8

typedef _Float16 f16;
typedef _Float16 h2_t __attribute__((ext_vector_type(2)));
typedef __fp16   g2_t __attribute__((ext_vector_type(2)));

union U32H2 { unsigned int u; h2_t h; g2_t g; };

__device__ inline unsigned int pkh2(float a, float b) {
    U32H2 v; v.g = __builtin_amdgcn_cvt_pkrtz(a, b); return v.u;
}
__device__ inline h2_t ash2(unsigned int u) { U32H2 v; v.u = u; return v.h; }

#if __has_builtin(__builtin_amdgcn_fdot2)
__device__ inline float fdot2f(unsigned int a, unsigned int b, float c) {
    return __builtin_amdgcn_fdot2(ash2(a), ash2(b), c, false);
}
#else
__device__ inline float fdot2f(unsigned int a, unsigned int b, float c) {
    h2_t ha = ash2(a), hb = ash2(b);
    return c + (float)ha.x*(float)hb.x + (float)ha.y*(float)hb.y;
}
#endif

// ws byte offsets
#define OFF_QG     0            // 32*64 f32       = 8192 B
#define OFF_QK16   8192         // 512*32 f16      = 32768 B
#define OFF_LPART  40960        // 16*32*32 f32    = 65536 B
#define OFF_VBUF   106496       // 16*4*512 f32    = 131072 B
#define OFF_OPART  237568       // 16*32*32*512 f16= 16777216 B  (total ~17.0 MB)

// ---------------- K1a: q[hq][d] = seed[j] @ Wq[head h].T + bq ----------------
__global__ __launch_bounds__(256) void k_q(
    const float* __restrict__ seed, const float* __restrict__ Wq,
    const float* __restrict__ bq, float* __restrict__ q_g)
{
    int hq = blockIdx.x; int h = hq >> 2; int j = hq & 3;
    int t = threadIdx.x;
    __shared__ float qpart[256];
    int d = t >> 2, q4 = t & 3;
    const float* sr = seed + j*DIM + q4*128;
    const float* wr = Wq + (size_t)(h*64 + d)*DIM + q4*128;
    float acc = 0.f;
    for (int c = 0; c < 128; c += 4) {
        float4 s4 = *(const float4*)(sr + c);
        float4 w4 = *(const float4*)(wr + c);
        acc += s4.x*w4.x + s4.y*w4.y + s4.z*w4.z + s4.w*w4.w;
    }
    qpart[t] = acc;
    __syncthreads();
    if (t < 64)
        q_g[hq*64 + t] = qpart[t*4] + qpart[t*4+1] + qpart[t*4+2] + qpart[t*4+3] + bq[h*64 + t];
}

// ---------------- K1b: qk16[c][hq] = (q[hq] @ Wk_head)/8, fp16 ----------------
// (k-bias and q@bk cancel in softmax -> dropped)
__global__ __launch_bounds__(256) void k_qk(
    const float* __restrict__ Wk, const float* __restrict__ q_g, f16* __restrict__ qk16)
{
    const int h = blockIdx.x;    // 0..7
    const int cs = blockIdx.y;   // 0..3
    const int t = threadIdx.x;
    __shared__ float q_s[4][64];
    __shared__ float red2[4][128];
    q_s[t >> 6][t & 63] = q_g[(h*4 + (t >> 6))*64 + (t & 63)];
    __syncthreads();
    const int c = cs*128 + (t & 127);
    const int dh = t >> 7;
    float a0=0.f, a1=0.f, a2=0.f, a3=0.f;
    const float* wb = Wk + ((size_t)(h*64 + dh*32))*DIM + c;
    #pragma unroll 8
    for (int d = 0; d < 32; ++d) {
        float w = wb[(size_t)d*DIM];                // coalesced across lanes
        a0 += q_s[0][dh*32 + d]*w;
        a1 += q_s[1][dh*32 + d]*w;
        a2 += q_s[2][dh*32 + d]*w;
        a3 += q_s[3][dh*32 + d]*w;
    }
    if (dh == 1) {
        red2[0][t & 127] = a0; red2[1][t & 127] = a1;
        red2[2][t & 127] = a2; red2[3][t & 127] = a3;
    }
    __syncthreads();
    if (dh == 0) {
        int ci = t & 127;
        qk16[(size_t)c*HQ + h*4 + 0] = (f16)((a0 + red2[0][ci]) * 0.125f);
        qk16[(size_t)c*HQ + h*4 + 1] = (f16)((a1 + red2[1][ci]) * 0.125f);
        qk16[(size_t)c*HQ + h*4 + 2] = (f16)((a2 + red2[2][ci]) * 0.125f);
        qk16[(size_t)c*HQ + h*4 + 3] = (f16)((a3 + red2[3][ci]) * 0.125f);
    }
}

// ---------------- K2: fused scores -> exp -> pool partials, one pass over X ----------------
// block = (chunk of 256 rows, b). 8 tiles of 32 rows. LDS = 48.4 KB -> 3 blocks/CU.
__global__ __launch_bounds__(256, 3) void k_att(
    const float* __restrict__ X, const f16* __restrict__ qk16,
    f16* __restrict__ opart, float* __restrict__ lpart)
{
    const int chunk = blockIdx.x, b = blockIdx.y;
    const int t = threadIdx.x;

    __shared__ f16 Xcm[512][36];      // [c][n] fp16, dword d of row c holds n=2d,2d+1
    __shared__ f16 sred[4][32][36];   // k-split score partials; reused as fp32 lred at end
    __shared__ f16 p_s[32][36];       // [hq][n] fp16

    unsigned int* XcmU = (unsigned int*)&Xcm[0][0];   // row stride 18 dwords
    const uint2* qkg = (const uint2*)qk16;            // row = 8 uint2

    const int g  = t >> 6;          // wave id = k-split group
    const int r4 = (t >> 3) & 7;    // phase A row-quad
    const int h4 = t & 7;           // phase A hq-quad
    const int rr = t >> 3;          // reduce role: row 0..31
    const int hh = (t & 7) << 2;    // reduce role: hq base
    const int hg = t >> 5;          // phase B: 4 hq at hg*4
    const int cg = t & 31;          // phase B: c lane
    const int rp = t >> 4;          // staging row-pair
    const int cq = (t & 15) << 1;   // staging c offset

    float o_acc[4][16];
    #pragma unroll
    for (int j = 0; j < 4; ++j)
        #pragma unroll
        for (int i = 0; i < 16; ++i) o_acc[j][i] = 0.f;
    float l_acc[4] = {0.f, 0.f, 0.f, 0.f};

    for (int tile = 0; tile < NTILE; ++tile) {
        const int r0 = chunk*CROWS + tile*TROWS;
        __syncthreads();   // prev tile's phase B done before overwriting Xcm/p_s
        // ---- stage X tile (32 rows x 512 c) as fp16 [c][n] ----
        {
            const float2* Xr0 = (const float2*)(X + ((size_t)b*NN + r0 + rp*2    )*DIM);
            const float2* Xr1 = (const float2*)(X + ((size_t)b*NN + r0 + rp*2 + 1)*DIM);
            #pragma unroll
            for (int cs = 0; cs < 16; ++cs) {
                int c0 = cs*32 + cq;
                float2 xa = Xr0[c0 >> 1];
                float2 xb = Xr1[c0 >> 1];
                XcmU[c0*18 + rp]     = pkh2(xa.x, xb.x);
                XcmU[(c0+1)*18 + rp] = pkh2(xa.y, xb.y);
            }
        }
        __syncthreads();
        // ---- phase A: s[r][hq] = X.qk (outer product, 4x4, k-split by wave) ----
        float sa[4][4];
        #pragma unroll
        for (int i = 0; i < 4; ++i)
            #pragma unroll
            for (int j = 0; j < 4; ++j) sa[i][j] = 0.f;
        {
            const int k0 = g << 7;
            #pragma unroll 4
            for (int k = k0; k < k0 + 128; ++k) {
                uint2 xu = *(const uint2*)&XcmU[k*18 + (r4 << 1)];   // rows 4r4..4r4+3
                uint2 qu = qkg[(size_t)k*8 + h4];                    // hq 4h4..4h4+3 (L1-hot)
                h2_t xA = ash2(xu.x), xB = ash2(xu.y);
                h2_t qA = ash2(qu.x), qB = ash2(qu.y);
                float x0=(float)xA.x, x1=(float)xA.y, x2=(float)xB.x, x3=(float)xB.y;
                float q0=(float)qA.x, q1=(float)qA.y, q2=(float)qB.x, q3=(float)qB.y;
                sa[0][0]+=x0*q0; sa[0][1]+=x0*q1; sa[0][2]+=x0*q2; sa[0][3]+=x0*q3;
                sa[1][0]+=x1*q0; sa[1][1]+=x1*q1; sa[1][2]+=x1*q2; sa[1][3]+=x1*q3;
                sa[2][0]+=x2*q0; sa[2][1]+=x2*q1; sa[2][2]+=x2*q2; sa[2][3]+=x2*q3;
                sa[3][0]+=x3*q0; sa[3][1]+=x3*q1; sa[3][2]+=x3*q2; sa[3][3]+=x3*q3;
            }
        }
        #pragma unroll
        for (int i = 0; i < 4; ++i) {
            uint2 w;
            w.x = pkh2(sa[i][0], sa[i][1]);
            w.y = pkh2(sa[i][2], sa[i][3]);
            *(uint2*)((char*)&sred[0][0][0] + ((size_t)((g*32 + r4*4 + i)*36 + h4*4)*2)) = w;
        }
        __syncthreads();
        // ---- reduce k-split, exp (bounded scores: no max needed), write p ----
        {
            float s0=0.f, s1=0.f, s2=0.f, s3=0.f;
            #pragma unroll
            for (int gg = 0; gg < 4; ++gg) {
                uint2 su = *(const uint2*)((const char*)&sred[0][0][0] + ((size_t)((gg*32 + rr)*36 + hh)*2));
                h2_t aa = ash2(su.x), bb = ash2(su.y);
                s0 += (float)aa.x; s1 += (float)aa.y; s2 += (float)bb.x; s3 += (float)bb.y;
            }
            float p0 = __expf(fminf(s0, 30.f));
            float p1 = __expf(fminf(s1, 30.f));
            float p2 = __expf(fminf(s2, 30.f));
            float p3 = __expf(fminf(s3, 30.f));
            l_acc[0] += p0; l_acc[1] += p1; l_acc[2] += p2; l_acc[3] += p3;
            p_s[hh+0][rr] = (f16)p0;
            p_s[hh+1][rr] = (f16)p1;
            p_s[hh+2][rr] = (f16)p2;
            p_s[hh+3][rr] = (f16)p3;
        }
        __syncthreads();
        // ---- phase B: o[hq][c] += p[hq][n]*X[n][c] via v_dot2_f32_f16 ----
        {
            const unsigned int* pU = (const unsigned int*)&p_s[0][0];
            #pragma unroll
            for (int ng = 0; ng < 4; ++ng) {
                unsigned int pd[4][4];
                #pragma unroll
                for (int j = 0; j < 4; ++j) {
                    uint2 pa = *(const uint2*)&pU[(hg*4 + j)*18 + ng*4];
                    uint2 pb = *(const uint2*)&pU[(hg*4 + j)*18 + ng*4 + 2];
                    pd[j][0] = pa.x; pd[j][1] = pa.y; pd[j][2] = pb.x; pd[j][3] = pb.y;
                }
                #pragma unroll
                for (int mm = 0; mm < 4; ++mm) {
                    #pragma unroll
                    for (int cc = 0; cc < 4; ++cc) {
                        const int c = cg + mm*32 + cc*128;
                        const int ci = mm*4 + cc;
                        const unsigned int* row = &XcmU[c*18 + ng*4];
                        uint2 xa = *(const uint2*)&row[0];
                        uint2 xb = *(const uint2*)&row[2];
                        #pragma unroll
                        for (int j = 0; j < 4; ++j) {
                            float a = o_acc[j][ci];
                            a = fdot2f(pd[j][0], xa.x, a);
                            a = fdot2f(pd[j][1], xa.y, a);
                            a = fdot2f(pd[j][2], xb.x, a);
                            a = fdot2f(pd[j][3], xb.y, a);
                            o_acc[j][ci] = a;
                        }
                    }
                }
            }
        }
    }
    // ---- block totals: l and fp16 o partials (no atomics) ----
    __syncthreads();
    float* lredf = (float*)&sred[0][0][0];   // [32][36] fp32 (4.6 KB <= 9.2 KB region)
    *(float4*)&lredf[rr*36 + hh] = make_float4(l_acc[0], l_acc[1], l_acc[2], l_acc[3]);
    __syncthreads();
    if (t < 32) {
        float l = 0.f;
        #pragma unroll
        for (int r = 0; r < 32; ++r) l += lredf[r*36 + t];
        lpart[((size_t)b*NCHUNK + chunk)*HQ + t] = l;
    }
    const size_t obase = (((size_t)b*NCHUNK + chunk)*HQ + hg*4)*DIM + cg;
    #pragma unroll
    for (int j = 0; j < 4; ++j)
        #pragma unroll
        for (int mm = 0; mm < 4; ++mm)
            #pragma unroll
            for (int cc = 0; cc < 4; ++cc)
                opart[obase + (size_t)j*DIM + mm*32 + cc*128] = (f16)o_acc[j][mm*4 + cc];
}

// ---------------- K3: reduce partials, normalize, fused Wv slice ----------------
// block (hq=(h,j), b) owns pooled[b][hq][0..511] and produces v[b][j][h*64..h*64+64)
__global__ __launch_bounds__(256) void k_red(
    const f16* __restrict__ opart, const float* __restrict__ lpart,
    const float* __restrict__ Wv, const float* __restrict__ bv,
    float* __restrict__ vbuf)
{
    const int hq = blockIdx.x, b = blockIdx.y;
    const int h = hq >> 2, j = hq & 3;
    const int t = threadIdx.x;
    __shared__ float pool_s[512];
    __shared__ float ls[32];
    __shared__ float linv_s;
    if (t < 32) ls[t] = lpart[((size_t)b*NCHUNK + t)*HQ + hq];
    __syncthreads();
    if (t == 0) {
        float l = 0.f;
        for (int i = 0; i < 32; ++i) l += ls[i];
        linv_s = 1.f / l;
    }
    float a0 = 0.f, a1 = 0.f;
    const unsigned int* opU = (const unsigned int*)opart;
    #pragma unroll 4
    for (int ch = 0; ch < 32; ++ch) {
        unsigned int u = opU[((((size_t)b*NCHUNK + ch)*HQ + hq) << 8) + t];
        h2_t hv = ash2(u);
        a0 += (float)hv.x; a1 += (float)hv.y;
    }
    __syncthreads();
    float linv = linv_s;
    pool_s[2*t]   = a0 * linv;
    pool_s[2*t+1] = a1 * linv;
    __syncthreads();
    const int o1 = t >> 2, q4 = t & 3;
    const float* wr = Wv + ((size_t)(h*64 + o1))*DIM + q4*128;
    const float* ps = pool_s + q4*128;
    float acc = 0.f;
    #pragma unroll 8
    for (int c = 0; c < 128; c += 4) {
        float4 w4 = *(const float4*)(wr + c);
        float4 p4 = *(const float4*)(ps + c);
        acc += w4.x*p4.x + w4.y*p4.y + w4.z*p4.z + w4.w*p4.w;
    }
    acc += __shfl_xor(acc, 1);
    acc += __shfl_xor(acc, 2);
    if (q4 == 0)
        vbuf[((size_t)b*KQn + j)*DIM + h*64 + o1] = acc + bv[h*64 + o1];
}

// ---------------- K4: Wo proj + residual + LayerNorm ----------------
__global__ __launch_bounds__(512) void k_wo_ln(
    const float* __restrict__ vbuf, const float* __restrict__ Wo, const float* __restrict__ bo,
    const float* __restrict__ seed, const float* __restrict__ gamma, const float* __restrict__ beta,
    float* __restrict__ out)
{
    const int j = blockIdx.x, b = blockIdx.y;
    const int t = threadIdx.x;
    __shared__ float v_s[512];
    __shared__ float wsum[8], wsq[8];
    v_s[t] = vbuf[((size_t)b*KQn + j)*DIM + t];
    __syncthreads();
    const float* wr = Wo + (size_t)t*DIM;
    float acc = bo[t];
    #pragma unroll 8
    for (int c = 0; c < 512; c += 4) {
        float4 w4 = *(const float4*)(wr + c);
        float4 p4 = *(const float4*)&v_s[c];
        acc += w4.x*p4.x + w4.y*p4.y + w4.z*p4.z + w4.w*p4.w;
    }
    float hv = acc + seed[j*DIM + t];
    float s1 = hv, s2 = hv*hv;
    #pragma unroll
    for (int m = 1; m <= 32; m <<= 1) {
        s1 += __shfl_xor(s1, m);
        s2 += __shfl_xor(s2, m);
    }
    if ((t & 63) == 0) { wsum[t >> 6] = s1; wsq[t >> 6] = s2; }
    __syncthreads();
    float tm = 0.f, tq = 0.f;
    #pragma unroll
    for (int i = 0; i < 8; ++i) { tm += wsum[i]; tq += wsq[i]; }
    float mu = tm * (1.f/512.f);
    float var = tq * (1.f/512.f) - mu*mu;
    float rs = rsqrtf(var + EPSLN);
    out[((size_t)b*KQn + j)*DIM + t] = (hv - mu)*rs*gamma[t] + beta[t];
}

extern "C" void kernel_launch(void* const* d_in, const int* in_sizes, int n_in,
                              void* d_out, int out_size, void* d_ws, size_t ws_size,
                              hipStream_t stream) {
    const float* X     = (const float*)d_in[0];
    const float* seed  = (const float*)d_in[1];
    const float* Wq    = (const float*)d_in[2];
    const float* bq    = (const float*)d_in[3];
    const float* Wk    = (const float*)d_in[4];
    // d_in[5] = bk : cancels in softmax, unused
    const float* Wv    = (const float*)d_in[6];
    const float* bv    = (const float*)d_in[7];
    const float* Wo    = (const float*)d_in[8];
    const float* bo    = (const float*)d_in[9];
    const float* gamma = (const float*)d_in[10];
    const float* beta  = (const float*)d_in[11];

    char* ws = (char*)d_ws;
    float* q_g   = (float*)(ws + OFF_QG);
    f16*   qk16  = (f16*)  (ws + OFF_QK16);
    float* lpart = (float*)(ws + OFF_LPART);
    float* vbuf  = (float*)(ws + OFF_VBUF);
    f16*   opart = (f16*)  (ws + OFF_OPART);
    float* out   = (float*)d_out;

    k_q    <<<32,               256, 0, stream>>>(seed, Wq, bq, q_g);
    k_qk   <<<dim3(8, 4),       256, 0, stream>>>(Wk, q_g, qk16);
    k_att  <<<dim3(NCHUNK, BB), 256, 0, stream>>>(X, qk16, opart, lpart);
    k_red  <<<dim3(HQ, BB),     256, 0, stream>>>(opart, lpart, Wv, bv, vbuf);
    k_wo_ln<<<dim3(KQn, BB),    512, 0, stream>>>(vbuf, Wo, bo, seed, gamma, beta, out);
}